// Round 1
// baseline (1223.968 us; speedup 1.0000x reference)
//
#include <hip/hip_runtime.h>

#define EPSF 1e-5f

__device__ __forceinline__ float fsig(float x){ return 1.0f/(1.0f+__expf(-x)); }
__device__ __forceinline__ float ftanh(float x){
  if (x >  15.f) return  1.f;
  if (x < -15.f) return -1.f;
  float e = __expf(2.f*x);
  return (e-1.f)/(e+1.f);
}

// ---------------------------------------------------------------------------
// Kernel 1: msum[t] = sum_{b,n} masks[b,t,n] + EPS   (one block per t)
// ---------------------------------------------------------------------------
__global__ void msum_kernel(const float* __restrict__ masks, float* __restrict__ msum){
  const int t   = blockIdx.x;
  const int tid = threadIdx.x;
  const int b0  = tid >> 3;          // 0..31
  const int n4  = (tid & 7) << 2;    // 0,4,...,28
  float s = 0.f;
  #pragma unroll 4
  for (int i = 0; i < 32; ++i) {
    const int b = b0 + (i << 5);
    const float4 v = *reinterpret_cast<const float4*>(masks + ((size_t)b*256 + t)*32 + n4);
    s += v.x + v.y + v.z + v.w;
  }
  __shared__ float red[256];
  red[tid] = s; __syncthreads();
  for (int off = 128; off > 0; off >>= 1) {
    if (tid < off) red[tid] += red[tid + off];
    __syncthreads();
  }
  if (tid == 0) msum[t] = red[0] + EPSF;
}

// ---------------------------------------------------------------------------
// Kernel 2: persistent RNN. 256 blocks x 256 threads, 4 batch elems / block.
// Thread tid owns LSTM gate row tid (128 weights in VGPRs).
// (bbh=tid>>6, jh=tid&63) owns h/c state element [bbh][jh].
// (bbq=tid>>5, nq=tid&31) (tid<128) owns the N=32-wide feature lanes.
// ---------------------------------------------------------------------------
__global__ __launch_bounds__(256) void rits_kernel(
  const float* __restrict__ values, const float* __restrict__ masks,
  const float* __restrict__ deltas, const float* __restrict__ labels,
  const float* __restrict__ is_train,
  const float* __restrict__ td_h_W, const float* __restrict__ td_h_b,
  const float* __restrict__ td_x_W, const float* __restrict__ td_x_b,
  const float* __restrict__ hist_W, const float* __restrict__ hist_b,
  const float* __restrict__ feat_W, const float* __restrict__ feat_b,
  const float* __restrict__ wc_W,  const float* __restrict__ wc_b,
  const float* __restrict__ W_ih,  const float* __restrict__ W_hh,
  const float* __restrict__ b_ih,  const float* __restrict__ b_hh,
  const float* __restrict__ out_W, const float* __restrict__ out_b,
  const float* __restrict__ msum,
  float* __restrict__ xl_acc, float* __restrict__ bce_acc,
  float* __restrict__ predictions, float* __restrict__ imps)
{
  // weights transposed so lane index is fastest-varying (conflict-free b32 reads)
  __shared__ __align__(16) float tdhT[32][64];   // [n][j] = td_h_W[j][n]
  __shared__ __align__(16) float thb[64];
  __shared__ __align__(16) float tdxd[32], tdxb[32];
  __shared__ __align__(16) float histT[64][32];  // [j][n] = hist_W[n][j]
  __shared__ __align__(16) float histb[32];
  __shared__ __align__(16) float featT[32][32];  // [k][n] = feat_W[n][k], diag=0
  __shared__ __align__(16) float featb[32];
  __shared__ __align__(16) float wcT[64][32];    // [k][n] = wc_W[n][k]
  __shared__ __align__(16) float wcb[32];
  __shared__ __align__(16) float outw[64];
  __shared__ __align__(16) float msum_l[256];
  // per-step activations
  __shared__ __align__(16) float ms[4][32], dls[4][32], gx[4][32];
  __shared__ __align__(16) float xc[4][32], cc[4][32];
  __shared__ __align__(16) float hl[4][64];
  __shared__ __align__(16) float gates[4][256];

  const int tid = threadIdx.x;
  const int b0  = blockIdx.x << 2;

  // ---- stage weights into LDS ----
  for (int i = tid; i < 2048; i += 256){ int j=i>>5, n=i&31; tdhT[n][j]=td_h_W[i]; }
  for (int i = tid; i < 2048; i += 256){ int n=i>>6, j=i&63; histT[j][n]=hist_W[i]; }
  for (int i = tid; i < 1024; i += 256){ int n=i>>5, k=i&31; featT[k][n]=(k==n)?0.f:feat_W[i]; }
  for (int i = tid; i < 2048; i += 256){ int n=i>>6, k=i&63; wcT[k][n]=wc_W[i]; }
  if (tid < 64) { thb[tid]=td_h_b[tid]; outw[tid]=out_W[tid]; }
  if (tid < 32) { tdxd[tid]=td_x_W[tid*33]; tdxb[tid]=td_x_b[tid];
                  histb[tid]=hist_b[tid]; featb[tid]=feat_b[tid]; wcb[tid]=wc_b[tid]; }
  msum_l[tid] = msum[tid];

  // ---- per-thread LSTM gate-row weights (stay in VGPRs for all 256 steps) ----
  float Wrow[128];
  {
    const float4* wi = reinterpret_cast<const float4*>(W_ih + (size_t)tid*64);
    const float4* wh = reinterpret_cast<const float4*>(W_hh + (size_t)tid*64);
    #pragma unroll
    for (int q = 0; q < 16; ++q){
      float4 v = wi[q];
      Wrow[4*q]=v.x; Wrow[4*q+1]=v.y; Wrow[4*q+2]=v.z; Wrow[4*q+3]=v.w;
    }
    #pragma unroll
    for (int q = 0; q < 16; ++q){
      float4 v = wh[q];
      Wrow[64+4*q]=v.x; Wrow[64+4*q+1]=v.y; Wrow[64+4*q+2]=v.z; Wrow[64+4*q+3]=v.w;
    }
  }
  const float bg = b_ih[tid] + b_hh[tid];

  const int bbh = tid >> 6;   // wave id -> batch elem for h/c state
  const int jh  = tid & 63;
  const int bbq = tid >> 5;   // (tid<128 only)
  const int nq  = tid & 31;

  float h_reg = 0.f, c_reg = 0.f;
  float loss_acc = 0.f;

  __syncthreads();

  for (int t = 0; t < 256; ++t) {
    const float msum_t = msum_l[t];
    float x_v = 0.f, m_v = 0.f, a1 = 0.f, xh_v = 0.f;

    // ---- A: load x,m,d ; gamma_x ----
    if (tid < 128) {
      const int base = ((b0 + bbq)*256 + t)*32 + nq;
      x_v = values[base];
      m_v = masks[base];
      const float d = deltas[base];
      ms[bbq][nq]  = m_v;
      dls[bbq][nq] = d;
      gx[bbq][nq]  = __expf(-fmaxf(fmaf(d, tdxd[nq], tdxb[nq]), 0.f));
    }
    __syncthreads();

    // ---- B: gamma_h ; h *= gamma_h ----
    {
      float acc = thb[jh];
      const float4* d4 = reinterpret_cast<const float4*>(dls[bbh]);
      #pragma unroll
      for (int q = 0; q < 8; ++q){
        float4 dv = d4[q];
        acc = fmaf(dv.x, tdhT[4*q  ][jh], acc);
        acc = fmaf(dv.y, tdhT[4*q+1][jh], acc);
        acc = fmaf(dv.z, tdhT[4*q+2][jh], acc);
        acc = fmaf(dv.w, tdhT[4*q+3][jh], acc);
      }
      h_reg *= __expf(-fmaxf(acc, 0.f));
      hl[bbh][jh] = h_reg;
    }
    __syncthreads();

    // ---- C: x_h ; x_c ; loss term 1 ----
    if (tid < 128) {
      float acc = histb[nq];
      const float4* h4 = reinterpret_cast<const float4*>(hl[bbq]);
      #pragma unroll
      for (int q = 0; q < 16; ++q){
        float4 hv = h4[q];
        acc = fmaf(hv.x, histT[4*q  ][nq], acc);
        acc = fmaf(hv.y, histT[4*q+1][nq], acc);
        acc = fmaf(hv.z, histT[4*q+2][nq], acc);
        acc = fmaf(hv.w, histT[4*q+3][nq], acc);
      }
      xh_v = acc;
      a1 = fabsf(x_v - acc) * m_v;
      xc[bbq][nq] = m_v * x_v + (1.f - m_v) * acc;
    }
    __syncthreads();

    // ---- D: z_h ; alpha ; c_h ; c_c ; loss terms 2,3 ; write imputation ----
    if (tid < 128) {
      float zacc = featb[nq], aacc = wcb[nq];
      const float4* x4 = reinterpret_cast<const float4*>(xc[bbq]);
      const float4* g4 = reinterpret_cast<const float4*>(gx[bbq]);
      const float4* m4 = reinterpret_cast<const float4*>(ms[bbq]);
      #pragma unroll
      for (int q = 0; q < 8; ++q){
        float4 xv = x4[q], gv = g4[q], mv = m4[q];
        zacc = fmaf(xv.x, featT[4*q  ][nq], zacc);
        zacc = fmaf(xv.y, featT[4*q+1][nq], zacc);
        zacc = fmaf(xv.z, featT[4*q+2][nq], zacc);
        zacc = fmaf(xv.w, featT[4*q+3][nq], zacc);
        aacc = fmaf(gv.x, wcT[4*q  ][nq], aacc);
        aacc = fmaf(gv.y, wcT[4*q+1][nq], aacc);
        aacc = fmaf(gv.z, wcT[4*q+2][nq], aacc);
        aacc = fmaf(gv.w, wcT[4*q+3][nq], aacc);
        aacc = fmaf(mv.x, wcT[32+4*q  ][nq], aacc);
        aacc = fmaf(mv.y, wcT[32+4*q+1][nq], aacc);
        aacc = fmaf(mv.z, wcT[32+4*q+2][nq], aacc);
        aacc = fmaf(mv.w, wcT[32+4*q+3][nq], aacc);
      }
      const float ch  = aacc * zacc + (1.f - aacc) * xh_v;
      const float a2  = fabsf(x_v - zacc) * m_v;
      const float a3  = fabsf(x_v - ch)   * m_v;
      loss_acc += (a1 + a2 + a3) / msum_t;
      const float ccv = m_v * x_v + (1.f - m_v) * ch;
      cc[bbq][nq] = ccv;
      imps[((b0 + bbq)*256 + t)*32 + nq] = ccv;
    }
    __syncthreads();

    // ---- E: LSTM gates (per-thread register weight row, LDS broadcast inputs) ----
    {
      #pragma unroll
      for (int bb = 0; bb < 4; ++bb){
        float g = bg;
        const float4* c4 = reinterpret_cast<const float4*>(cc[bb]);
        const float4* m4 = reinterpret_cast<const float4*>(ms[bb]);
        const float4* h4 = reinterpret_cast<const float4*>(hl[bb]);
        #pragma unroll
        for (int q = 0; q < 8; ++q){
          float4 v = c4[q];
          g = fmaf(v.x, Wrow[4*q  ], g);
          g = fmaf(v.y, Wrow[4*q+1], g);
          g = fmaf(v.z, Wrow[4*q+2], g);
          g = fmaf(v.w, Wrow[4*q+3], g);
        }
        #pragma unroll
        for (int q = 0; q < 8; ++q){
          float4 v = m4[q];
          g = fmaf(v.x, Wrow[32+4*q  ], g);
          g = fmaf(v.y, Wrow[32+4*q+1], g);
          g = fmaf(v.z, Wrow[32+4*q+2], g);
          g = fmaf(v.w, Wrow[32+4*q+3], g);
        }
        #pragma unroll
        for (int q = 0; q < 16; ++q){
          float4 v = h4[q];
          g = fmaf(v.x, Wrow[64+4*q  ], g);
          g = fmaf(v.y, Wrow[64+4*q+1], g);
          g = fmaf(v.z, Wrow[64+4*q+2], g);
          g = fmaf(v.w, Wrow[64+4*q+3], g);
        }
        gates[bb][tid] = g;
      }
    }
    __syncthreads();

    // ---- F: LSTM pointwise update ----
    {
      const float ig = gates[bbh][jh];
      const float fg = gates[bbh][64+jh];
      const float gg = gates[bbh][128+jh];
      const float og = gates[bbh][192+jh];
      c_reg = fsig(fg)*c_reg + fsig(ig)*ftanh(gg);
      h_reg = fsig(og)*ftanh(c_reg);
    }
    __syncthreads();
  }

  // ---- epilogue: final h, loss reduce, predictions + bce ----
  hl[bbh][jh] = h_reg;
  float* red = &gates[0][0];
  red[tid] = loss_acc;
  __syncthreads();
  for (int off = 128; off > 0; off >>= 1){
    if (tid < off) red[tid] += red[tid + off];
    __syncthreads();
  }
  if (tid == 0) atomicAdd(xl_acc, red[0]);
  if (tid < 4) {
    float y = out_b[0];
    #pragma unroll
    for (int j = 0; j < 64; ++j) y = fmaf(hl[tid][j], outw[j], y);
    predictions[b0 + tid] = fsig(y);
    const float lab = labels[b0 + tid];
    const float it  = is_train[b0 + tid];
    const float mv  = fmaxf(-y, 0.f);
    const float bce = y - y*lab + mv + __logf(__expf(-mv) + __expf(-y - mv));
    atomicAdd(bce_acc, bce * it);
  }
}

// ---------------------------------------------------------------------------
// Kernel 3: finalize loss scalar
// ---------------------------------------------------------------------------
__global__ void final_kernel(const float* __restrict__ is_train,
                             const float* __restrict__ ws,
                             float* __restrict__ out){
  const int tid = threadIdx.x;
  __shared__ float red[256];
  red[tid] = is_train[tid] + is_train[tid+256] + is_train[tid+512] + is_train[tid+768];
  __syncthreads();
  for (int off = 128; off > 0; off >>= 1){
    if (tid < off) red[tid] += red[tid + off];
    __syncthreads();
  }
  if (tid == 0){
    const float yl = ws[1] / (red[0] + EPSF);
    out[0] = ws[0] / 256.0f + 0.1f * yl;
  }
}

extern "C" void kernel_launch(void* const* d_in, const int* in_sizes, int n_in,
                              void* d_out, int out_size, void* d_ws, size_t ws_size,
                              hipStream_t stream){
  const float* values   = (const float*)d_in[0];
  const float* masks    = (const float*)d_in[1];
  const float* deltas   = (const float*)d_in[2];
  // d_in[3] evals, d_in[4] eval_masks: unused by forward outputs
  const float* labels   = (const float*)d_in[5];
  const float* is_train = (const float*)d_in[6];
  const float* td_h_W   = (const float*)d_in[7];
  const float* td_h_b   = (const float*)d_in[8];
  const float* td_x_W   = (const float*)d_in[9];
  const float* td_x_b   = (const float*)d_in[10];
  const float* hist_W   = (const float*)d_in[11];
  const float* hist_b   = (const float*)d_in[12];
  const float* feat_W   = (const float*)d_in[13];
  const float* feat_b   = (const float*)d_in[14];
  const float* wc_W     = (const float*)d_in[15];
  const float* wc_b     = (const float*)d_in[16];
  const float* W_ih     = (const float*)d_in[17];
  const float* W_hh     = (const float*)d_in[18];
  const float* b_ih     = (const float*)d_in[19];
  const float* b_hh     = (const float*)d_in[20];
  const float* out_W    = (const float*)d_in[21];
  const float* out_b    = (const float*)d_in[22];

  float* out = (float*)d_out;                 // [0]=loss, [1..1025)=preds, [1025..)=imps
  float* ws  = (float*)d_ws;                  // [0]=xl_sum, [1]=bce_sum, [2..258)=msum

  hipMemsetAsync(ws, 0, 2*sizeof(float), stream);
  msum_kernel<<<256, 256, 0, stream>>>(masks, ws + 2);
  rits_kernel<<<256, 256, 0, stream>>>(values, masks, deltas, labels, is_train,
      td_h_W, td_h_b, td_x_W, td_x_b, hist_W, hist_b, feat_W, feat_b,
      wc_W, wc_b, W_ih, W_hh, b_ih, b_hh, out_W, out_b,
      ws + 2, ws + 0, ws + 1, out + 1, out + 1 + 1024);
  final_kernel<<<1, 256, 0, stream>>>(is_train, ws, out);
}